// Round 1
// baseline (563.434 us; speedup 1.0000x reference)
//
#include <hip/hip_runtime.h>
#include <math.h>

#define NPTS 100000
#define CDIM 64
#define KNN  16

// ---------------------------------------------------------------------------
// Kernel A: q/k/v projections.  y = feats @ W  (W already [in][out]).
// Block: 256 threads, 64 rows of feats.  LDS: 3x Wq/Wk/Wv (48KB) + feats tile
// (16KB) = 64KB -> 2 blocks/CU.  Thread t: col c = t&63, wave rg = t>>6 owns
// rows rg*16..rg*16+15, processed as two register-blocked groups of 8 rows so
// each sW read amortizes over 8 rows and sF reads are float4 broadcasts.
// ---------------------------------------------------------------------------
__global__ __launch_bounds__(256) void proj_qkv(
    const float* __restrict__ feats,
    const float* __restrict__ Wq, const float* __restrict__ Wk,
    const float* __restrict__ Wv,
    float* __restrict__ q, float* __restrict__ k, float* __restrict__ v)
{
    __shared__ float sW[3 * 64 * 64];
    __shared__ float sF[64 * 64];
    const int t = threadIdx.x;

    for (int i = t; i < 1024; i += 256) {
        ((float4*)sW)[i]        = ((const float4*)Wq)[i];
        ((float4*)sW)[1024 + i] = ((const float4*)Wk)[i];
        ((float4*)sW)[2048 + i] = ((const float4*)Wv)[i];
    }
    const long rbase = (long)blockIdx.x * 64;
    for (int i = t; i < 1024; i += 256) {
        long row = rbase + (i >> 4);
        float4 val = make_float4(0.f, 0.f, 0.f, 0.f);
        if (row < NPTS) val = ((const float4*)feats)[row * 16 + (i & 15)];
        ((float4*)sF)[i] = val;
    }
    __syncthreads();

    const int c  = t & 63;
    const int rg = t >> 6;

    #pragma unroll
    for (int g = 0; g < 2; ++g) {
        const int r0 = rg * 16 + g * 8;
        float aq[8], ak[8], av[8];
        #pragma unroll
        for (int r = 0; r < 8; ++r) { aq[r] = 0.f; ak[r] = 0.f; av[r] = 0.f; }

        #pragma unroll
        for (int j4 = 0; j4 < 16; ++j4) {
            float4 f[8];
            #pragma unroll
            for (int r = 0; r < 8; ++r)
                f[r] = ((const float4*)sF)[(r0 + r) * 16 + j4];
            #pragma unroll
            for (int jj = 0; jj < 4; ++jj) {
                const int j = j4 * 4 + jj;
                const float wq = sW[j * 64 + c];
                const float wk = sW[4096 + j * 64 + c];
                const float wv = sW[8192 + j * 64 + c];
                #pragma unroll
                for (int r = 0; r < 8; ++r) {
                    const float fv = (&f[r].x)[jj];
                    aq[r] += fv * wq;
                    ak[r] += fv * wk;
                    av[r] += fv * wv;
                }
            }
        }
        #pragma unroll
        for (int r = 0; r < 8; ++r) {
            const long grow = rbase + r0 + r;
            if (grow < NPTS) {
                q[grow * 64 + c] = aq[r];
                k[grow * 64 + c] = ak[r];
                v[grow * 64 + c] = av[r];
            }
        }
    }
}

// ---------------------------------------------------------------------------
// Kernel B: per-point kNN attention + fused output projection.
// One wave per point; lane = h*8+d channel (matches reshape(N,H,D) order).
// Scores: per-neighbor dot over D=8 via shfl_xor within the 8-lane head
// group.  Softmax over the 16 per-lane score registers (replicated within a
// head -- harmless).  Weighted V accumulates from 16 cached v registers.
// Fused epilogue: out[c] = bo[c] + sum_j attn[j]*Wo[j][c], attn[j] broadcast
// via __shfl (uniform src lane -> v_readlane), Wo staged in LDS.
// N = 100000 = 25000 blocks * 4 waves exactly, so no bounds checks.
// ---------------------------------------------------------------------------
__global__ __launch_bounds__(256) void attn_out(
    const float* __restrict__ q, const float* __restrict__ k,
    const float* __restrict__ v, const int* __restrict__ knn,
    const float* __restrict__ Wo, const float* __restrict__ bo,
    float* __restrict__ out)
{
    __shared__ float sWo[64 * 64];
    __shared__ float sbo[64];
    const int t = threadIdx.x;
    for (int i = t; i < 1024; i += 256)
        ((float4*)sWo)[i] = ((const float4*)Wo)[i];
    if (t < 16) ((float4*)sbo)[t] = ((const float4*)bo)[t];
    __syncthreads();

    const int lane = t & 63;
    const long n = (long)blockIdx.x * 4 + (t >> 6);

    const float qv = q[n * 64 + lane];
    const int idx_l = (lane < KNN) ? knn[n * KNN + lane] : 0;

    float vr[KNN], sc[KNN];
    #pragma unroll
    for (int kk = 0; kk < KNN; ++kk) {
        const int nb = __shfl(idx_l, kk);
        const long base = (long)nb * 64 + lane;
        const float kv = k[base];
        vr[kk] = v[base];
        float p = qv * kv;
        p += __shfl_xor(p, 1);
        p += __shfl_xor(p, 2);
        p += __shfl_xor(p, 4);
        sc[kk] = p * 0.3535533905932738f;   // 1/sqrt(8)
    }

    float m = sc[0];
    #pragma unroll
    for (int kk = 1; kk < KNN; ++kk) m = fmaxf(m, sc[kk]);
    float s = 0.f;
    #pragma unroll
    for (int kk = 0; kk < KNN; ++kk) { sc[kk] = __expf(sc[kk] - m); s += sc[kk]; }
    const float inv = 1.f / s;

    float acc = 0.f;
    #pragma unroll
    for (int kk = 0; kk < KNN; ++kk) acc += sc[kk] * vr[kk];
    acc *= inv;

    float o = sbo[lane];
    #pragma unroll
    for (int j = 0; j < 64; ++j) {
        const float a = __shfl(acc, j);
        o += a * sWo[j * 64 + lane];
    }
    out[n * 64 + lane] = o;
}

extern "C" void kernel_launch(void* const* d_in, const int* in_sizes, int n_in,
                              void* d_out, int out_size, void* d_ws, size_t ws_size,
                              hipStream_t stream) {
    const float* feats = (const float*)d_in[0];
    const int*   knn   = (const int*)d_in[1];
    const float* Wq    = (const float*)d_in[2];
    const float* Wk    = (const float*)d_in[3];
    const float* Wv    = (const float*)d_in[4];
    const float* Wo    = (const float*)d_in[5];
    const float* bo    = (const float*)d_in[6];
    float* out = (float*)d_out;

    float* q = (float*)d_ws;               // 6.4M floats
    float* k = q + (size_t)NPTS * CDIM;    // 6.4M floats
    float* v = k + (size_t)NPTS * CDIM;    // 6.4M floats  (total 76.8 MB)

    proj_qkv<<<(NPTS + 63) / 64, 256, 0, stream>>>(feats, Wq, Wk, Wv, q, k, v);
    attn_out<<<NPTS / 4, 256, 0, stream>>>(q, k, v, knn, Wo, bo, out);
}

// Round 2
// 307.156 us; speedup vs baseline: 1.8344x; 1.8344x over previous
//
#include <hip/hip_runtime.h>
#include <math.h>

#define NPTS 100000
#define CDIM 64
#define KNN  16

// ---------------------------------------------------------------------------
// Kernel A: q/k/v projection, y = feats @ W.
// lane = row.  Each thread keeps its feats row (64 floats) in VGPRs; W lives
// in LDS and is read as wave-uniform ds_read_b128 broadcasts (4 output cols
// at a time, row-major, 16B-aligned, static offsets).  Per 4-col block:
// 64 broadcast b128 + 256 v_fmac -> fma-bound, ~100 VGPRs, no spill.
// Grid is (row tiles) x 3 matrices for balance; 16KB LDS per block.
// ---------------------------------------------------------------------------
__global__ __launch_bounds__(256) void proj_qkv(
    const float* __restrict__ feats,
    const float* __restrict__ Wq, const float* __restrict__ Wk,
    const float* __restrict__ Wv,
    float* __restrict__ q, float* __restrict__ k, float* __restrict__ v)
{
    __shared__ float sW[64 * 64];
    const int t = threadIdx.x;
    const int m = blockIdx.x % 3;              // which matrix
    const long tile = blockIdx.x / 3;          // row tile (256 rows)

    const float* W = (m == 0) ? Wq : (m == 1) ? Wk : Wv;
    float* out     = (m == 0) ? q  : (m == 1) ? k  : v;

    for (int i = t; i < 1024; i += 256)
        ((float4*)sW)[i] = ((const float4*)W)[i];

    const long row = tile * 256 + t;
    const bool valid = row < NPTS;
    const long lrow = valid ? row : (NPTS - 1);

    float f[64];
    {
        const float4* fr = (const float4*)(feats + lrow * 64);
        #pragma unroll
        for (int i = 0; i < 16; ++i) {
            float4 x = fr[i];
            f[4 * i + 0] = x.x; f[4 * i + 1] = x.y;
            f[4 * i + 2] = x.z; f[4 * i + 3] = x.w;
        }
    }
    __syncthreads();

    float4* orow = (float4*)(out + row * 64);

    #pragma unroll 1
    for (int cb = 0; cb < 16; ++cb) {
        const float4* wp = (const float4*)(sW + cb * 4);   // wp[j*16] = W[j][4cb..4cb+3]
        float ax = 0.f, ay = 0.f, az = 0.f, aw = 0.f;
        #pragma unroll
        for (int j = 0; j < 64; ++j) {
            const float4 w = wp[j * 16];                   // ds_read_b128, uniform addr
            const float fj = f[j];
            ax += fj * w.x; ay += fj * w.y; az += fj * w.z; aw += fj * w.w;
        }
        if (valid) orow[cb] = make_float4(ax, ay, az, aw);
    }
}

// ---------------------------------------------------------------------------
// Kernel B: per-point kNN attention + fused output projection.
// One wave per point; lane = h*8+d channel (matches reshape(N,H,D) order).
// Scores via shfl_xor within the 8-lane head group; softmax over 16 score
// regs; fused Wo epilogue via __shfl broadcast against LDS-resident Wo.
// N = 100000 = 25000 blocks * 4 waves exactly.
// ---------------------------------------------------------------------------
__global__ __launch_bounds__(256) void attn_out(
    const float* __restrict__ q, const float* __restrict__ k,
    const float* __restrict__ v, const int* __restrict__ knn,
    const float* __restrict__ Wo, const float* __restrict__ bo,
    float* __restrict__ out)
{
    __shared__ float sWo[64 * 64];
    __shared__ float sbo[64];
    const int t = threadIdx.x;
    for (int i = t; i < 1024; i += 256)
        ((float4*)sWo)[i] = ((const float4*)Wo)[i];
    if (t < 16) ((float4*)sbo)[t] = ((const float4*)bo)[t];
    __syncthreads();

    const int lane = t & 63;
    const long n = (long)blockIdx.x * 4 + (t >> 6);

    const float qv = q[n * 64 + lane];
    const int idx_l = (lane < KNN) ? knn[n * KNN + lane] : 0;

    float vr[KNN], sc[KNN];
    #pragma unroll
    for (int kk = 0; kk < KNN; ++kk) {
        const int nb = __shfl(idx_l, kk);
        const long base = (long)nb * 64 + lane;
        const float kv = k[base];
        vr[kk] = v[base];
        float p = qv * kv;
        p += __shfl_xor(p, 1);
        p += __shfl_xor(p, 2);
        p += __shfl_xor(p, 4);
        sc[kk] = p * 0.3535533905932738f;   // 1/sqrt(8)
    }

    float m = sc[0];
    #pragma unroll
    for (int kk = 1; kk < KNN; ++kk) m = fmaxf(m, sc[kk]);
    float s = 0.f;
    #pragma unroll
    for (int kk = 0; kk < KNN; ++kk) { sc[kk] = __expf(sc[kk] - m); s += sc[kk]; }
    const float inv = 1.f / s;

    float acc = 0.f;
    #pragma unroll
    for (int kk = 0; kk < KNN; ++kk) acc += sc[kk] * vr[kk];
    acc *= inv;

    float o = sbo[lane];
    #pragma unroll
    for (int j = 0; j < 64; ++j) {
        const float a = __shfl(acc, j);
        o += a * sWo[j * 64 + lane];
    }
    out[n * 64 + lane] = o;
}

extern "C" void kernel_launch(void* const* d_in, const int* in_sizes, int n_in,
                              void* d_out, int out_size, void* d_ws, size_t ws_size,
                              hipStream_t stream) {
    const float* feats = (const float*)d_in[0];
    const int*   knn   = (const int*)d_in[1];
    const float* Wq    = (const float*)d_in[2];
    const float* Wk    = (const float*)d_in[3];
    const float* Wv    = (const float*)d_in[4];
    const float* Wo    = (const float*)d_in[5];
    const float* bo    = (const float*)d_in[6];
    float* out = (float*)d_out;

    float* q = (float*)d_ws;               // 6.4M floats
    float* k = q + (size_t)NPTS * CDIM;
    float* v = k + (size_t)NPTS * CDIM;    // total 76.8 MB

    const int ntiles = (NPTS + 255) / 256;             // 391
    proj_qkv<<<ntiles * 3, 256, 0, stream>>>(feats, Wq, Wk, Wv, q, k, v);
    attn_out<<<NPTS / 4, 256, 0, stream>>>(q, k, v, knn, Wo, bo, out);
}

// Round 4
// 237.495 us; speedup vs baseline: 2.3724x; 1.2933x over previous
//
#include <hip/hip_runtime.h>
#include <hip/hip_fp16.h>
#include <math.h>

#define NPTS 100000
#define CDIM 64
#define KNN  16

typedef unsigned int uint;

// DPP butterfly add: lane gets x + x[lane^mask]; CTRL must be an immediate,
// so it is a template parameter.
template <int CTRL>
__device__ __forceinline__ float dpp_add(float x) {
    int yi = __builtin_amdgcn_mov_dpp(__float_as_int(x), CTRL, 0xF, 0xF, true);
    return x + __int_as_float(yi);
}

// ---------------------------------------------------------------------------
// Kernel A: fused q/k/v projection, y = feats @ W.  1 thread = 1 row.
// W is read with wave-uniform addresses -> compiler emits s_load (scalar pipe,
// no LDS, no VALU cost for the broadcast).  acc[64] lives in VGPRs with only
// static indexing; feats row is re-chunked 8 floats per jo step (L1-hot on
// the 2nd/3rd matrix).  q stored fp32; k,v stored f16-interleaved:
// kv[n][c] = (f16(k) | f16(v)<<16)  -> one dword gather per channel later.
// ---------------------------------------------------------------------------
__global__ __launch_bounds__(64, 2) void proj_qkv(
    const float* __restrict__ feats,
    const float* __restrict__ Wq, const float* __restrict__ Wk,
    const float* __restrict__ Wv,
    float* __restrict__ q, uint* __restrict__ kv)
{
    const long row = (long)blockIdx.x * 64 + threadIdx.x;
    const bool valid = row < NPTS;
    const long lrow = valid ? row : (NPTS - 1);
    const float4* fr = (const float4*)(feats + lrow * 64);

    float acc[64];
    uint kb[32];

    // ---------------- q ----------------
    #pragma unroll
    for (int c = 0; c < 64; ++c) acc[c] = 0.f;
    #pragma unroll 1
    for (int jo = 0; jo < 8; ++jo) {
        const float4 fa = fr[jo * 2], fb = fr[jo * 2 + 1];
        const float fch[8] = {fa.x, fa.y, fa.z, fa.w, fb.x, fb.y, fb.z, fb.w};
        #pragma unroll
        for (int ji = 0; ji < 8; ++ji) {
            const float fj = fch[ji];
            const float4* wr = (const float4*)(Wq + (size_t)(jo * 8 + ji) * 64);
            #pragma unroll
            for (int c4 = 0; c4 < 16; ++c4) {
                const float4 w = wr[c4];           // uniform -> s_load
                acc[4*c4+0] += fj * w.x; acc[4*c4+1] += fj * w.y;
                acc[4*c4+2] += fj * w.z; acc[4*c4+3] += fj * w.w;
            }
        }
    }
    if (valid) {
        float4* orow = (float4*)(q + row * 64);
        #pragma unroll
        for (int c4 = 0; c4 < 16; ++c4)
            orow[c4] = make_float4(acc[4*c4], acc[4*c4+1], acc[4*c4+2], acc[4*c4+3]);
    }

    // ---------------- k (held as packed f16 pairs) ----------------
    #pragma unroll
    for (int c = 0; c < 64; ++c) acc[c] = 0.f;
    #pragma unroll 1
    for (int jo = 0; jo < 8; ++jo) {
        const float4 fa = fr[jo * 2], fb = fr[jo * 2 + 1];
        const float fch[8] = {fa.x, fa.y, fa.z, fa.w, fb.x, fb.y, fb.z, fb.w};
        #pragma unroll
        for (int ji = 0; ji < 8; ++ji) {
            const float fj = fch[ji];
            const float4* wr = (const float4*)(Wk + (size_t)(jo * 8 + ji) * 64);
            #pragma unroll
            for (int c4 = 0; c4 < 16; ++c4) {
                const float4 w = wr[c4];
                acc[4*c4+0] += fj * w.x; acc[4*c4+1] += fj * w.y;
                acc[4*c4+2] += fj * w.z; acc[4*c4+3] += fj * w.w;
            }
        }
    }
    #pragma unroll
    for (int i = 0; i < 32; ++i) {
        const uint h0 = __half_as_ushort(__float2half(acc[2*i]));
        const uint h1 = __half_as_ushort(__float2half(acc[2*i+1]));
        kb[i] = h0 | (h1 << 16);
    }

    // ---------------- v (combine with k, store kv) ----------------
    #pragma unroll
    for (int c = 0; c < 64; ++c) acc[c] = 0.f;
    #pragma unroll 1
    for (int jo = 0; jo < 8; ++jo) {
        const float4 fa = fr[jo * 2], fb = fr[jo * 2 + 1];
        const float fch[8] = {fa.x, fa.y, fa.z, fa.w, fb.x, fb.y, fb.z, fb.w};
        #pragma unroll
        for (int ji = 0; ji < 8; ++ji) {
            const float fj = fch[ji];
            const float4* wr = (const float4*)(Wv + (size_t)(jo * 8 + ji) * 64);
            #pragma unroll
            for (int c4 = 0; c4 < 16; ++c4) {
                const float4 w = wr[c4];
                acc[4*c4+0] += fj * w.x; acc[4*c4+1] += fj * w.y;
                acc[4*c4+2] += fj * w.z; acc[4*c4+3] += fj * w.w;
            }
        }
    }
    if (valid) {
        uint4* krow = (uint4*)(kv + row * 64);
        #pragma unroll
        for (int i = 0; i < 16; ++i) {     // words 4i..4i+3 from kb[2i],kb[2i+1]
            const uint v0 = (uint)__half_as_ushort(__float2half(acc[4*i]));
            const uint v1 = (uint)__half_as_ushort(__float2half(acc[4*i+1]));
            const uint v2 = (uint)__half_as_ushort(__float2half(acc[4*i+2]));
            const uint v3 = (uint)__half_as_ushort(__float2half(acc[4*i+3]));
            uint4 o;
            o.x = (kb[2*i]   & 0xffffu) | (v0 << 16);
            o.y = (kb[2*i]   >> 16)     | (v1 << 16);
            o.z = (kb[2*i+1] & 0xffffu) | (v2 << 16);
            o.w = (kb[2*i+1] >> 16)     | (v3 << 16);
            krow[i] = o;
        }
    }
}

// ---------------------------------------------------------------------------
// Kernel B: per-point kNN attention -> o_mid (pre-Wo).  1 wave = 1 point,
// lane = h*8+d channel.  knn row via readfirstlane -> s_load (SGPR indices);
// one dword gather per neighbor (f16 k|v pair); dot over D=8 via DPP butterfly
// (xor1, xor2, xor7==row_half_mirror) -- zero DS-pipe ops in the whole kernel.
// ---------------------------------------------------------------------------
__global__ __launch_bounds__(256) void attn_mid(
    const float* __restrict__ q, const uint* __restrict__ kv,
    const int* __restrict__ knn, float* __restrict__ o_mid)
{
    const int t = threadIdx.x;
    const int lane = t & 63;
    const int n = blockIdx.x * 4 + (t >> 6);
    const int ns = __builtin_amdgcn_readfirstlane(n);

    const float qv = q[(size_t)n * 64 + lane];

    const int* kr = knn + (size_t)ns * KNN;
    int idx[KNN];
    #pragma unroll
    for (int i = 0; i < KNN; ++i) idx[i] = kr[i];   // uniform -> s_load

    float sc[KNN], vr[KNN];
    #pragma unroll
    for (int i = 0; i < KNN; ++i) {
        const uint w = kv[(size_t)idx[i] * 64 + lane];
        const float2 kvf = __half22float2(*(const __half2*)&w);
        vr[i] = kvf.y;
        float p = qv * kvf.x;
        p = dpp_add<0xB1>(p);    // quad_perm xor 1
        p = dpp_add<0x4E>(p);    // quad_perm xor 2
        p = dpp_add<0x141>(p);   // row_half_mirror == xor 7
        sc[i] = p * 0.3535533905932738f;   // 1/sqrt(8)
    }

    float m = sc[0];
    #pragma unroll
    for (int i = 1; i < KNN; ++i) m = fmaxf(m, sc[i]);
    float s = 0.f;
    #pragma unroll
    for (int i = 0; i < KNN; ++i) { sc[i] = __expf(sc[i] - m); s += sc[i]; }
    const float inv = 1.f / s;

    float acc = 0.f;
    #pragma unroll
    for (int i = 0; i < KNN; ++i) acc += sc[i] * vr[i];

    o_mid[(size_t)n * 64 + lane] = acc * inv;
}

// ---------------------------------------------------------------------------
// Kernel C: out = o_mid @ Wo + bo.  Same s_load-W skeleton as kernel A.
// ---------------------------------------------------------------------------
__global__ __launch_bounds__(64, 2) void out_proj(
    const float* __restrict__ o_mid, const float* __restrict__ Wo,
    const float* __restrict__ bo, float* __restrict__ out)
{
    const long row = (long)blockIdx.x * 64 + threadIdx.x;
    const bool valid = row < NPTS;
    const long lrow = valid ? row : (NPTS - 1);
    const float4* fr = (const float4*)(o_mid + lrow * 64);

    float acc[64];
    const float4* br = (const float4*)bo;
    #pragma unroll
    for (int c4 = 0; c4 < 16; ++c4) {       // uniform -> s_load
        const float4 b = br[c4];
        acc[4*c4+0] = b.x; acc[4*c4+1] = b.y; acc[4*c4+2] = b.z; acc[4*c4+3] = b.w;
    }
    #pragma unroll 1
    for (int jo = 0; jo < 8; ++jo) {
        const float4 fa = fr[jo * 2], fb = fr[jo * 2 + 1];
        const float fch[8] = {fa.x, fa.y, fa.z, fa.w, fb.x, fb.y, fb.z, fb.w};
        #pragma unroll
        for (int ji = 0; ji < 8; ++ji) {
            const float fj = fch[ji];
            const float4* wr = (const float4*)(Wo + (size_t)(jo * 8 + ji) * 64);
            #pragma unroll
            for (int c4 = 0; c4 < 16; ++c4) {
                const float4 w = wr[c4];
                acc[4*c4+0] += fj * w.x; acc[4*c4+1] += fj * w.y;
                acc[4*c4+2] += fj * w.z; acc[4*c4+3] += fj * w.w;
            }
        }
    }
    if (valid) {
        float4* orow = (float4*)(out + row * 64);
        #pragma unroll
        for (int c4 = 0; c4 < 16; ++c4)
            orow[c4] = make_float4(acc[4*c4], acc[4*c4+1], acc[4*c4+2], acc[4*c4+3]);
    }
}

extern "C" void kernel_launch(void* const* d_in, const int* in_sizes, int n_in,
                              void* d_out, int out_size, void* d_ws, size_t ws_size,
                              hipStream_t stream) {
    const float* feats = (const float*)d_in[0];
    const int*   knn   = (const int*)d_in[1];
    const float* Wq    = (const float*)d_in[2];
    const float* Wk    = (const float*)d_in[3];
    const float* Wv    = (const float*)d_in[4];
    const float* Wo    = (const float*)d_in[5];
    const float* bo    = (const float*)d_in[6];
    float* out = (float*)d_out;

    float* q     = (float*)d_ws;                       // 25.6 MB
    uint*  kvbuf = (uint*)(q + (size_t)NPTS * CDIM);   // 25.6 MB
    float* o_mid = (float*)(kvbuf + (size_t)NPTS * CDIM); // 25.6 MB

    const int nt = (NPTS + 63) / 64;   // 1563
    proj_qkv<<<nt, 64, 0, stream>>>(feats, Wq, Wk, Wv, q, kvbuf);
    attn_mid<<<NPTS / 4, 256, 0, stream>>>(q, kvbuf, knn, o_mid);
    out_proj<<<nt, 64, 0, stream>>>(o_mid, Wo, bo, out);
}